// Round 4
// baseline (443.208 us; speedup 1.0000x reference)
//
#include <hip/hip_runtime.h>
#include <hip/hip_bf16.h>
#include <math.h>

// Problem constants
#define NC 3
#define NK 64
#define KK 3
#define K2 9
#define PAD 1
#define SCALE 4
#define S2 16
#define MID 4
#define B 4
#define H 128
#define W 128
#define HW (H*W)          // 16384
#define CIN 67            // NK + NC
#define OUT_HW (H*SCALE)  // 512
#define CST 64            // pixel-major xcat row: 64 bf16 (128 B)

typedef short bf16x8 __attribute__((ext_vector_type(8)));
typedef float f32x4 __attribute__((ext_vector_type(4)));
typedef float f32x2 __attribute__((ext_vector_type(2)));
typedef unsigned int u32x4 __attribute__((ext_vector_type(4)));
typedef unsigned int u32x2 __attribute__((ext_vector_type(2)));

__device__ __forceinline__ float fast_sigmoid(float v) { return 1.f / (1.f + __expf(-v)); }
__device__ __forceinline__ float fast_tanh(float v) { return 2.f / (1.f + __expf(-2.f * v)) - 1.f; }

// fp32 -> bf16 round-to-nearest-even (the verified-correct conversion —
// v_cvt_pk_bf16_f32 regressed absmax 0.016 -> 0.141 in R2, do not use)
__device__ __forceinline__ unsigned short f2bf(float f) {
    unsigned int u = __float_as_uint(f);
    unsigned int r = (u + 0x7FFFu + ((u >> 16) & 1u)) >> 16;
    return (unsigned short)r;
}

// unpack a u32 holding 2 bf16 into a float2 {lo, hi}
__device__ __forceinline__ f32x2 unpk(unsigned int u) {
    f32x2 r;
    r[0] = __uint_as_float(u << 16);
    r[1] = __uint_as_float(u & 0xffff0000u);
    return r;
}

// load a zero-padded 3x3 patch of one channel plane (HxW) at (y,x)
__device__ __forceinline__ void load_patch(const float* __restrict__ xc, int y, int x, float* p) {
#pragma unroll
    for (int dy = -1; dy <= 1; dy++) {
#pragma unroll
        for (int dx = -1; dx <= 1; dx++) {
            int yy = y + dy, xx = x + dx;
            float v = (yy >= 0 && yy < H && xx >= 0 && xx < W) ? xc[yy * W + xx] : 0.f;
            p[(dy + 1) * 3 + (dx + 1)] = v;
        }
    }
}

// ---------------------------------------------------------------------------
// Prepack LSTM weights into M=192 A-fragments (12 M-tiles), bf16.
// ---------------------------------------------------------------------------
__global__ void k_prepL(const float* __restrict__ lw, unsigned short* __restrict__ aplk) {
    int g = blockIdx.x;            // M-tile 0..11
    int tid = threadIdx.x;         // 0..511
    int lane = tid >> 3, j = tid & 7;
    int o = g * 16 + (lane & 15);
    int k = ((lane >> 4) << 3) + j;
    float val = 0.f;
    if (k < 27) {
        int c = k / 9, tap = k % 9;
        int gate = o >> 6, nk = o & 63;
        int base = (gate == 0) ? 0 : (gate == 1) ? 2 * NK : 3 * NK;
        val = lw[(size_t)(base + nk) * (CIN * 9) + c * 9 + tap];
    }
    aplk[(size_t)g * 512 + tid] = f2bf(val);
}

// ---------------------------------------------------------------------------
// ConvLSTM as MFMA implicit GEMM. Also writes lrp (pixel-major lr channels)
// from wave 0 — fuses the former k_lr kernel.
// ---------------------------------------------------------------------------
__global__ __launch_bounds__(256, 4) void k_lstm(const float* __restrict__ X,
                                                 const unsigned short* __restrict__ aplk,
                                                 const float* __restrict__ lb,
                                                 unsigned short* __restrict__ xcatA,
                                                 float* __restrict__ hid_out,
                                                 float* __restrict__ cell_out,
                                                 float* __restrict__ lrp) {
    int tid = threadIdx.x;
    int lane = tid & 63;
    int nt = __builtin_amdgcn_readfirstlane(tid >> 6);
    int blk = blockIdx.x;
    int sg = (blk & 7) * 128 + (blk >> 3);
    int b = sg >> 8;
    int hwbase = (sg & 255) * 64;
    int n = lane & 15, q = lane >> 4;
    int hw = hwbase + nt * 16 + n;
    int y = hw >> 7, x = hw & (W - 1);

    // fused k_lr: wave 0 writes the pixel-major lr channels for this block's 64 px
    if (nt == 0) {
        int px = hwbase + lane;
        f32x4 v = {X[(size_t)(b * NC + 0) * HW + px], X[(size_t)(b * NC + 1) * HW + px],
                   X[(size_t)(b * NC + 2) * HW + px], 0.f};
        *(f32x4*)(lrp + ((size_t)b * HW + px) * 4) = v;
    }

    // B-fragment: 8 patch samples, k = q*8+j
    bf16x8 bf;
#pragma unroll
    for (int j = 0; j < 8; j++) {
        int k = q * 8 + j;
        float v = 0.f;
        if (k < 27) {
            int c = k / 9, tap = k % 9;
            int ky = tap / 3, kx = tap % 3;
            int yy = y + ky - 1, xx = x + kx - 1;
            if (yy >= 0 && yy < H && xx >= 0 && xx < W)
                v = X[(size_t)(b * NC + c) * HW + yy * W + xx];
        }
        bf[j] = (short)f2bf(v);
    }

    f32x4 acc[12];
#pragma unroll
    for (int mt = 0; mt < 12; mt++) { f32x4 z = {0.f, 0.f, 0.f, 0.f}; acc[mt] = z; }
#pragma unroll
    for (int mt = 0; mt < 12; mt++) {
        bf16x8 af = *(const bf16x8*)(aplk + (size_t)mt * 512 + lane * 8);
        acc[mt] = __builtin_amdgcn_mfma_f32_16x16x32_bf16(af, bf, acc[mt], 0, 0, 0);
    }

    unsigned short* xo = xcatA + ((size_t)b * HW + hw) * CST;
#pragma unroll
    for (int mt = 0; mt < 4; mt++) {
        float hv4[4];
#pragma unroll
        for (int r = 0; r < 4; r++) {
            int nk = mt * 16 + q * 4 + r;
            float gi = acc[mt][r] + lb[nk];
            float go = acc[mt + 4][r] + lb[2 * NK + nk];
            float gg = acc[mt + 8][r] + lb[3 * NK + nk];
            float cv = fast_sigmoid(gi) * fast_tanh(gg);
            float hv = fast_sigmoid(go) * fast_tanh(cv);
            hv4[r] = hv;
            hid_out[(size_t)(b * NK + nk) * HW + hw] = hv;
            cell_out[(size_t)(b * NK + nk) * HW + hw] = cv;
        }
        u32x2 st;
        st[0] = (unsigned int)f2bf(hv4[0]) | ((unsigned int)f2bf(hv4[1]) << 16);
        st[1] = (unsigned int)f2bf(hv4[2]) | ((unsigned int)f2bf(hv4[3]) << 16);
        *(u32x2*)(xo + mt * 16 + q * 4) = st;
    }
}

// ---------------------------------------------------------------------------
// Prepack deform weights dw[o<64][c<67][k<9] into MFMA A-fragment order, bf16.
// ---------------------------------------------------------------------------
__global__ void k_prepA(const float* __restrict__ w, unsigned short* __restrict__ apk) {
    int g = blockIdx.x;            // (tap*3+ks)*4+mt
    int tid = threadIdx.x;         // 0..511
    int lane = tid >> 3, j = tid & 7;
    int mt = g & 3, r = g >> 2;    // r = tap*3+ks
    int ks = r % 3, tap = r / 3;
    int o = mt * 16 + (lane & 15);
    int c = ks * 32 + ((lane >> 4) << 3) + j;
    float val = (c < CIN) ? w[(size_t)o * (CIN * 9) + c * 9 + tap] : 0.f;
    apk[(size_t)g * 512 + tid] = f2bf(val);
}

// Prepack offset(18)+mask(9) conv weights into M=32 A-fragments, bf16.
__global__ void k_prepOM(const float* __restrict__ ow, const float* __restrict__ mw,
                         unsigned short* __restrict__ apk) {
    int g = blockIdx.x;            // (tap*3+kss)*2+mt
    int tid = threadIdx.x;         // 0..511
    int lane = tid >> 3, j = tid & 7;
    int mt = g & 1, r = g >> 1;    // r = tap*3+kss
    int kss = r % 3, tap = r / 3;
    int o = mt * 16 + (lane & 15);
    int c = kss * 32 + ((lane >> 4) << 3) + j;
    float val = 0.f;
    if (c < CIN) {
        if (o < 18) val = ow[(size_t)o * (CIN * 9) + c * 9 + tap];
        else if (o < 27) val = mw[(size_t)(o - 18) * (CIN * 9) + c * 9 + tap];
    }
    apk[(size_t)g * 512 + tid] = f2bf(val);
}

// ---------------------------------------------------------------------------
// FUSED offset/mask conv + deformable conv — wave-independent, 2-DEEP
// SOFTWARE-PIPELINED. Block = 4 waves, each wave owns 16 px end-to-end.
// Both phases double-buffer the next tap's loads over the current tap's
// blend+MFMA (tap loops fully unrolled -> all buffer indices compile-time).
// Arithmetic identical to the verified R3 version.
// ---------------------------------------------------------------------------
__global__ __launch_bounds__(256, 4) void k_offdef(const unsigned short* __restrict__ xcat,
                                                   const float* __restrict__ lrp,
                                                   const unsigned short* __restrict__ apkom,
                                                   const float* __restrict__ ob,
                                                   const float* __restrict__ mb,
                                                   const unsigned short* __restrict__ apk,
                                                   const float* __restrict__ bias,
                                                   unsigned short* __restrict__ xout) {
    __shared__ float somp[4][16][37];   // 9472 B; stride 37: conflict-free reads
    int tid = threadIdx.x;
    int lane = tid & 63;
    int wid = __builtin_amdgcn_readfirstlane(tid >> 6);
    int blk = blockIdx.x;                    // 0..1023
    int sg = (blk & 7) * 128 + (blk >> 3);   // XCD-contiguous strip id
    int b = sg >> 8;
    int hwbase = (sg & 255) * 64;
    int n = lane & 15, q = lane >> 4;
    int hw = hwbase + wid * 16 + n;
    int y = hw >> 7, x = hw & (W - 1);

    const unsigned short* xb = xcat + (size_t)b * HW * CST;
    const float* lb_ = lrp + (size_t)b * HW * 4;

    // ---------------- phase 1: offset+mask conv, 2-deep pipelined ---------
    {
        f32x4 acc2[2];
#pragma unroll
        for (int mt = 0; mt < 2; mt++) { f32x4 z = {0.f, 0.f, 0.f, 0.f}; acc2[mt] = z; }

        u32x4 p1d[2][2];   // [buf][kss] staged xcat fragments
        int p1ii[2];
        bool p1v[2];
        auto p1_issue = [&](int tap, int buf) {
            int ky = tap / 3, kx = tap - ky * 3;
            int yy = y + ky - 1, xx = x + kx - 1;
            bool vld = (yy >= 0 && yy < H && xx >= 0 && xx < W);
            int ii = min(max(yy, 0), H - 1) * W + min(max(xx, 0), W - 1);
            p1v[buf] = vld;
            p1ii[buf] = ii;
            const unsigned short* xr = xb + ((size_t)ii << 6);
            p1d[buf][0] = *(const u32x4*)(xr + q * 8);
            p1d[buf][1] = *(const u32x4*)(xr + 32 + q * 8);
        };
        auto p1_consume = [&](int tap, int buf) {
            const unsigned short* ab = apkom + (size_t)(tap * 6) * 512 + lane * 8;
            bool vld = p1v[buf];
            // lr load issued early, consumed last
            f32x4 L = {0.f, 0.f, 0.f, 0.f};
            if (q == 0 && vld) L = *(const f32x4*)(lb_ + ((size_t)p1ii[buf] << 2));
#pragma unroll
            for (int kss = 0; kss < 2; kss++) {
                bf16x8 bfv;
                if (vld) bfv = *(const bf16x8*)&p1d[buf][kss];
                else { bf16x8 z = {0, 0, 0, 0, 0, 0, 0, 0}; bfv = z; }
#pragma unroll
                for (int mt = 0; mt < 2; mt++) {
                    bf16x8 af = *(const bf16x8*)(ab + (size_t)(kss * 2 + mt) * 512);
                    acc2[mt] = __builtin_amdgcn_mfma_f32_16x16x32_bf16(af, bfv, acc2[mt], 0, 0, 0);
                }
            }
            bf16x8 bf2 = {0, 0, 0, 0, 0, 0, 0, 0};
            if (q == 0 && vld) {
#pragma unroll
                for (int j = 0; j < 4; j++) bf2[j] = (short)f2bf(L[j]);
            }
#pragma unroll
            for (int mt = 0; mt < 2; mt++) {
                bf16x8 af = *(const bf16x8*)(ab + (size_t)(4 + mt) * 512);
                acc2[mt] = __builtin_amdgcn_mfma_f32_16x16x32_bf16(af, bf2, acc2[mt], 0, 0, 0);
            }
        };

        p1_issue(0, 0);
#pragma unroll
        for (int tap = 0; tap < K2; tap++) {
            int cur = tap & 1;                      // compile-time after unroll
            if (tap < K2 - 1) p1_issue(tap + 1, cur ^ 1);
            p1_consume(tap, cur);
        }

        // LDS transpose: lane (n,q) holds o = mt*16+q*4+r for pixel n
#pragma unroll
        for (int mt = 0; mt < 2; mt++)
#pragma unroll
            for (int r = 0; r < 4; r++) {
                int o = mt * 16 + q * 4 + r;
                float s = acc2[mt][r];
                if (o < 18)
                    somp[wid][n][(o >> 1) * 4 + (o & 1)] = s + ob[o];
                else if (o < 27)
                    somp[wid][n][(o - 18) * 4 + 2] = 2.f * fast_sigmoid(s + mb[o - 18]);
            }
    }
    __syncthreads();

    // ---------------- phase 2: deformable conv, 2-deep pipelined ----------
    f32x4 acc[4];
#pragma unroll
    for (int mt = 0; mt < 4; mt++) { f32x4 z = {0.f, 0.f, 0.f, 0.f}; acc[mt] = z; }

    float cA00[2], cA01[2], cA10[2], cA11[2];
    int cJ00[2], cJ01[2], cJ10[2], cJ11[2];
    u32x4 d00[2][2], d01[2][2], d10[2][2], d11[2][2];   // [buf][ks]

    auto p2_issue = [&](int tap, int buf) {
        float omy = somp[wid][n][tap * 4 + 0];
        float omx = somp[wid][n][tap * 4 + 1];
        float m = somp[wid][n][tap * 4 + 2];
        int ky = tap / 3, kx = tap - ky * 3;
        float py = (float)(y + ky - 1) + omy;
        float px_ = (float)(x + kx - 1) + omx;
        float fy = floorf(py), fx = floorf(px_);
        float wy = py - fy, wx = px_ - fx;
        int y0 = (int)fy, x0 = (int)fx;
        int y1 = y0 + 1, x1 = x0 + 1;
        float vy0 = (y0 >= 0 && y0 <= H - 1) ? 1.f : 0.f;
        float vy1 = (y1 >= 0 && y1 <= H - 1) ? 1.f : 0.f;
        float vx0 = (x0 >= 0 && x0 <= W - 1) ? 1.f : 0.f;
        float vx1 = (x1 >= 0 && x1 <= W - 1) ? 1.f : 0.f;
        int yc0 = min(max(y0, 0), H - 1), yc1 = min(max(y1, 0), H - 1);
        int xc0 = min(max(x0, 0), W - 1), xc1 = min(max(x1, 0), W - 1);
        cA00[buf] = (1.f - wy) * (1.f - wx) * m * vy0 * vx0;
        cA01[buf] = (1.f - wy) * wx * m * vy0 * vx1;
        cA10[buf] = wy * (1.f - wx) * m * vy1 * vx0;
        cA11[buf] = wy * wx * m * vy1 * vx1;
        int j00 = yc0 * W + xc0, j01 = yc0 * W + xc1;
        int j10 = yc1 * W + xc0, j11 = yc1 * W + xc1;
        cJ00[buf] = j00; cJ01[buf] = j01; cJ10[buf] = j10; cJ11[buf] = j11;
        const unsigned short* r00 = xb + ((size_t)j00 << 6);
        const unsigned short* r01 = xb + ((size_t)j01 << 6);
        const unsigned short* r10 = xb + ((size_t)j10 << 6);
        const unsigned short* r11 = xb + ((size_t)j11 << 6);
#pragma unroll
        for (int ks = 0; ks < 2; ks++) {
            int c0 = ks * 32 + q * 8;
            d00[buf][ks] = *(const u32x4*)(r00 + c0);
            d01[buf][ks] = *(const u32x4*)(r01 + c0);
            d10[buf][ks] = *(const u32x4*)(r10 + c0);
            d11[buf][ks] = *(const u32x4*)(r11 + c0);
        }
    };

    auto p2_consume = [&](int tap, int buf) {
        const unsigned short* ab = apk + (size_t)(tap * 12) * 512 + lane * 8;
        float a00 = cA00[buf], a01 = cA01[buf], a10 = cA10[buf], a11 = cA11[buf];
        // lr loads issued early (covered by ks0/ks1 blend + 8 MFMAs)
        f32x4 L00, L01, L10, L11;
        if (q == 0) {
            L00 = *(const f32x4*)(lb_ + ((size_t)cJ00[buf] << 2));
            L01 = *(const f32x4*)(lb_ + ((size_t)cJ01[buf] << 2));
            L10 = *(const f32x4*)(lb_ + ((size_t)cJ10[buf] << 2));
            L11 = *(const f32x4*)(lb_ + ((size_t)cJ11[buf] << 2));
        }
#pragma unroll
        for (int ks = 0; ks < 2; ks++) {
            bf16x8 bf;
            unsigned int* bfu = (unsigned int*)&bf;
#pragma unroll
            for (int e = 0; e < 4; e++) {
                f32x2 v = unpk(d00[buf][ks][e]) * a00 + unpk(d01[buf][ks][e]) * a01
                        + unpk(d10[buf][ks][e]) * a10 + unpk(d11[buf][ks][e]) * a11;
                bfu[e] = (unsigned int)f2bf(v[0]) | ((unsigned int)f2bf(v[1]) << 16);
            }
#pragma unroll
            for (int mt = 0; mt < 4; mt++) {
                bf16x8 af = *(const bf16x8*)(ab + (size_t)(ks * 4 + mt) * 512);
                acc[mt] = __builtin_amdgcn_mfma_f32_16x16x32_bf16(af, bf, acc[mt], 0, 0, 0);
            }
        }
        bf16x8 bf2 = {0, 0, 0, 0, 0, 0, 0, 0};
        if (q == 0) {
            f32x4 Lv = L00 * a00 + L01 * a01 + L10 * a10 + L11 * a11;
#pragma unroll
            for (int j = 0; j < 4; j++) bf2[j] = (short)f2bf(Lv[j]);
        }
#pragma unroll
        for (int mt = 0; mt < 4; mt++) {
            bf16x8 af = *(const bf16x8*)(ab + (size_t)(2 * 4 + mt) * 512);
            acc[mt] = __builtin_amdgcn_mfma_f32_16x16x32_bf16(af, bf2, acc[mt], 0, 0, 0);
        }
    };

    p2_issue(0, 0);
#pragma unroll
    for (int tap = 0; tap < K2; tap++) {
        int cur = tap & 1;                          // compile-time after unroll
        if (tap < K2 - 1) p2_issue(tap + 1, cur ^ 1);
        p2_consume(tap, cur);
    }

    // direct epilogue: lane (n,q) stores o = mt*16+q*4+r for its pixel
    unsigned short* xo = xout + ((size_t)b * HW + hw) * CST;
#pragma unroll
    for (int mt = 0; mt < 4; mt++) {
        float s[4];
#pragma unroll
        for (int r = 0; r < 4; r++) {
            int o = mt * 16 + q * 4 + r;
            s[r] = acc[mt][r] + bias[o];
        }
        u32x2 st;
        st[0] = (unsigned int)f2bf(s[0]) | ((unsigned int)f2bf(s[1]) << 16);
        st[1] = (unsigned int)f2bf(s[2]) | ((unsigned int)f2bf(s[3]) << 16);
        *(u32x2*)(xo + mt * 16 + q * 4) = st;
    }
}

// ---------------------------------------------------------------------------
// Final 3-channel conv, tap-split across 4 waves with LDS reduction.
// ---------------------------------------------------------------------------
__global__ __launch_bounds__(256, 4) void k_conv3(const unsigned short* __restrict__ xcat,
                                                  const float* __restrict__ lrp,
                                                  const float* __restrict__ cw,
                                                  const float* __restrict__ cb,
                                                  float* __restrict__ y3) {
    __shared__ float red[4 * 3 * 64];  // 3072 B
    int tid = threadIdx.x;
    int lane = tid & 63;
    int wid = __builtin_amdgcn_readfirstlane(tid >> 6);
    int blk = blockIdx.x;
    int sg = (blk & 7) * 128 + (blk >> 3);
    int b = sg >> 8;
    int hwbase = (sg & 255) * 64;
    int hw = hwbase + lane;
    int y = hw >> 7, x = hw & (W - 1);
    int t0 = (wid == 0) ? 0 : 3 + (wid - 1) * 2;
    int t1 = (wid == 0) ? 3 : t0 + 2;

    float a0 = 0.f, a1 = 0.f, a2 = 0.f;
    const unsigned short* xb = xcat + (size_t)b * HW * CST;
    const float* lb_ = lrp + (size_t)b * HW * 4;
#pragma unroll 1
    for (int tap = t0; tap < t1; tap++) {
        int ky = tap / 3, kx = tap - ky * 3;
        int yy = y + ky - 1, xx = x + kx - 1;
        if (yy < 0 || yy >= H || xx < 0 || xx >= W) continue;
        int ii = yy * W + xx;
        const unsigned short* xr = xb + ((size_t)ii << 6);
#pragma unroll
        for (int c8 = 0; c8 < 8; c8++) {
            u32x4 d = *(const u32x4*)(xr + c8 * 8);
#pragma unroll
            for (int e = 0; e < 4; e++) {
                int c = c8 * 8 + e * 2;
                float lo = __uint_as_float(d[e] << 16);
                float hi = __uint_as_float(d[e] & 0xffff0000u);
                a0 += lo * cw[0 * (CIN * 9) + c * 9 + tap] + hi * cw[0 * (CIN * 9) + (c + 1) * 9 + tap];
                a1 += lo * cw[1 * (CIN * 9) + c * 9 + tap] + hi * cw[1 * (CIN * 9) + (c + 1) * 9 + tap];
                a2 += lo * cw[2 * (CIN * 9) + c * 9 + tap] + hi * cw[2 * (CIN * 9) + (c + 1) * 9 + tap];
            }
        }
        f32x4 L = *(const f32x4*)(lb_ + ((size_t)ii << 2));
#pragma unroll
        for (int e = 0; e < 3; e++) {
            a0 += L[e] * cw[0 * (CIN * 9) + (64 + e) * 9 + tap];
            a1 += L[e] * cw[1 * (CIN * 9) + (64 + e) * 9 + tap];
            a2 += L[e] * cw[2 * (CIN * 9) + (64 + e) * 9 + tap];
        }
    }
    red[(wid * 3 + 0) * 64 + lane] = a0;
    red[(wid * 3 + 1) * 64 + lane] = a1;
    red[(wid * 3 + 2) * 64 + lane] = a2;
    __syncthreads();
    if (tid < 192) {
        int oc = tid >> 6, px = tid & 63;
        float s = red[(0 * 3 + oc) * 64 + px] + red[(1 * 3 + oc) * 64 + px]
                + red[(2 * 3 + oc) * 64 + px] + red[(3 * 3 + oc) * 64 + px];
        y3[(size_t)(b * NC + oc) * HW + hwbase + px] = s + cb[oc];
    }
}

// global average pool: one block per (b,c)
__global__ __launch_bounds__(256) void k_pool(const float* __restrict__ y3,
                                              float* __restrict__ pooled) {
    int bc = blockIdx.x;  // 0..11
    const float* p = y3 + (size_t)bc * HW;
    float s = 0.f;
    for (int i = threadIdx.x; i < HW; i += 256) s += p[i];
    __shared__ float red[256];
    red[threadIdx.x] = s;
    __syncthreads();
    for (int off = 128; off > 0; off >>= 1) {
        if (threadIdx.x < off) red[threadIdx.x] += red[threadIdx.x + off];
        __syncthreads();
    }
    if (threadIdx.x == 0) pooled[bc] = red[0] / (float)HW;
}

// ---------------------------------------------------------------------------
// Fused DDF upsample: spatial conv + dynamic combine + pixel_shuffle + clip.
// Computes the tiny per-branch channel MLP in-block (fused k_ch).
// ---------------------------------------------------------------------------
__global__ __launch_bounds__(256) void k_ddf(const float* __restrict__ y3,
                                             const float* __restrict__ spw,
                                             const float* __restrict__ spb,
                                             const float* __restrict__ pooled,
                                             const float* __restrict__ ch_w1,
                                             const float* __restrict__ ch_b1,
                                             const float* __restrict__ ch_w2,
                                             const float* __restrict__ ch_b2,
                                             float* __restrict__ out) {
    __shared__ float s_spw[4 * K2 * NC * 9];  // 972
    __shared__ float s_spb[4 * K2];           // 36
    __shared__ float s_ch[4 * NC * K2];       // 108
    int t = blockIdx.x * blockDim.x + threadIdx.x;
    int b = t >> 14, hw = t & (HW - 1), y = hw >> 7, x = hw & (W - 1);
    int s0 = blockIdx.y * 4;
    for (int i = threadIdx.x; i < 4 * K2 * NC * 9; i += 256) s_spw[i] = spw[s0 * K2 * NC * 9 + i];
    if (threadIdx.x < 4 * K2) s_spb[threadIdx.x] = spb[s0 * K2 + threadIdx.x];
    if (threadIdx.x < 4 * NC * K2) {
        int t2 = threadIdx.x;
        int si = t2 / (NC * K2), kk = t2 - si * (NC * K2);
        int s = s0 + si;
        float a = ch_b2[s * (NC * K2) + kk];
#pragma unroll
        for (int m = 0; m < MID; m++) {
            float h1 = ch_b1[s * MID + m];
#pragma unroll
            for (int c = 0; c < NC; c++) h1 += pooled[b * NC + c] * ch_w1[(s * MID + m) * NC + c];
            a += fmaxf(h1, 0.f) * ch_w2[(s * (NC * K2) + kk) * MID + m];
        }
        s_ch[t2] = a;
    }
    __syncthreads();
    float p[NC][9];
#pragma unroll
    for (int c = 0; c < NC; c++) load_patch(y3 + (b * NC + c) * HW, y, x, p[c]);
#pragma unroll
    for (int si = 0; si < 4; si++) {
        int s = s0 + si;
        float spv[K2];
#pragma unroll
        for (int k = 0; k < K2; k++) {
            float a = s_spb[si * K2 + k];
            const float* w = s_spw + (si * K2 + k) * (NC * 9);
#pragma unroll
            for (int c = 0; c < NC; c++)
#pragma unroll
                for (int tt = 0; tt < 9; tt++) a += p[c][tt] * w[c * 9 + tt];
            spv[k] = a;
        }
        int sy = s >> 2, sx = s & 3;
#pragma unroll
        for (int c = 0; c < NC; c++) {
            float a = 0.f;
            const float* chp = s_ch + (si * NC + c) * K2;
#pragma unroll
            for (int k = 0; k < K2; k++) a += p[c][k] * (chp[k] + spv[k]);
            a = fminf(fmaxf(a, 0.f), 255.f);
            out[((size_t)(b * NC + c) * OUT_HW + (y * SCALE + sy)) * OUT_HW + (x * SCALE + sx)] = a;
        }
    }
}

extern "C" void kernel_launch(void* const* d_in, const int* in_sizes, int n_in,
                              void* d_out, int out_size, void* d_ws, size_t ws_size,
                              hipStream_t stream) {
    const float* X = (const float*)d_in[0];
    const float* lstm_w = (const float*)d_in[1];
    const float* lstm_b = (const float*)d_in[2];
    const float* ow[3] = {(const float*)d_in[3], (const float*)d_in[9], (const float*)d_in[15]};
    const float* ob[3] = {(const float*)d_in[4], (const float*)d_in[10], (const float*)d_in[16]};
    const float* mw[3] = {(const float*)d_in[5], (const float*)d_in[11], (const float*)d_in[17]};
    const float* mb[3] = {(const float*)d_in[6], (const float*)d_in[12], (const float*)d_in[18]};
    const float* dw[3] = {(const float*)d_in[7], (const float*)d_in[13], (const float*)d_in[19]};
    const float* db[3] = {(const float*)d_in[8], (const float*)d_in[14], (const float*)d_in[20]};
    const float* conv_w = (const float*)d_in[21];
    const float* conv_b = (const float*)d_in[22];
    const float* sp_w = (const float*)d_in[23];
    const float* sp_b = (const float*)d_in[24];
    const float* ch_w1 = (const float*)d_in[25];
    const float* ch_b1 = (const float*)d_in[26];
    const float* ch_w2 = (const float*)d_in[27];
    const float* ch_b2 = (const float*)d_in[28];

    float* out = (float*)d_out;
    const size_t OUT_IMG = (size_t)B * NC * OUT_HW * OUT_HW;  // 3145728
    const size_t HIDSZ = (size_t)B * NK * HW;                 // 4194304
    float* hid_out = out + OUT_IMG;
    float* cell_out = out + OUT_IMG + HIDSZ;

    float* ws = (float*)d_ws;
    const size_t XCATF = (size_t)B * HW * CST / 2;  // bf16 xcat, in float units
    unsigned short* xcatA = (unsigned short*)ws;  ws += XCATF;
    unsigned short* xcatB = (unsigned short*)ws;  ws += XCATF;
    float* lrp = ws;              ws += (size_t)B * HW * 4;
    unsigned short* apk[3];
    for (int i = 0; i < 3; i++) { apk[i] = (unsigned short*)ws; ws += 108 * 512 / 2; }
    unsigned short* apkOM[3];
    for (int i = 0; i < 3; i++) { apkOM[i] = (unsigned short*)ws; ws += 54 * 512 / 2; }
    unsigned short* aplk = (unsigned short*)ws;  ws += 12 * 512 / 2;
    float* y3 = ws;               ws += (size_t)B * NC * HW;
    float* pooled = ws;           ws += 16;

    dim3 blk(256);
    dim3 g4(B * HW / 256, 4);
    dim3 gd(B * HW / 64);         // 1024 strips (64 px per block, 16 per wave)

    k_prepL<<<dim3(12), dim3(512), 0, stream>>>(lstm_w, aplk);
    for (int i = 0; i < 3; i++) {
        k_prepA<<<dim3(108), dim3(512), 0, stream>>>(dw[i], apk[i]);
        k_prepOM<<<dim3(54), dim3(512), 0, stream>>>(ow[i], mw[i], apkOM[i]);
    }
    k_lstm<<<gd, blk, 0, stream>>>(X, aplk, lstm_b, xcatA, hid_out, cell_out, lrp);

    // layer 1: xcatA -> xcatB (offmask fused into deform, pipelined)
    k_offdef<<<gd, blk, 0, stream>>>(xcatA, lrp, apkOM[0], ob[0], mb[0], apk[0], db[0], xcatB);
    // layer 2: xcatB -> xcatA
    k_offdef<<<gd, blk, 0, stream>>>(xcatB, lrp, apkOM[1], ob[1], mb[1], apk[1], db[1], xcatA);
    // layer 3: xcatA -> xcatB
    k_offdef<<<gd, blk, 0, stream>>>(xcatA, lrp, apkOM[2], ob[2], mb[2], apk[2], db[2], xcatB);

    k_conv3<<<gd, blk, 0, stream>>>(xcatB, lrp, conv_w, conv_b, y3);
    k_pool<<<dim3(B * NC), blk, 0, stream>>>(y3, pooled);
    k_ddf<<<g4, blk, 0, stream>>>(y3, sp_w, sp_b, pooled, ch_w1, ch_b1, ch_w2, ch_b2, out);
}

// Round 5
// 408.560 us; speedup vs baseline: 1.0848x; 1.0848x over previous
//
#include <hip/hip_runtime.h>
#include <hip/hip_bf16.h>
#include <math.h>

// Problem constants
#define NC 3
#define NK 64
#define KK 3
#define K2 9
#define PAD 1
#define SCALE 4
#define S2 16
#define MID 4
#define B 4
#define H 128
#define W 128
#define HW (H*W)          // 16384
#define CIN 67            // NK + NC
#define OUT_HW (H*SCALE)  // 512
#define CST 64            // pixel-major xcat row: 64 bf16 (128 B)

typedef short bf16x8 __attribute__((ext_vector_type(8)));
typedef float f32x4 __attribute__((ext_vector_type(4)));
typedef float f32x2 __attribute__((ext_vector_type(2)));
typedef unsigned int u32x4 __attribute__((ext_vector_type(4)));
typedef unsigned int u32x2 __attribute__((ext_vector_type(2)));

__device__ __forceinline__ float fast_sigmoid(float v) { return 1.f / (1.f + __expf(-v)); }
__device__ __forceinline__ float fast_tanh(float v) { return 2.f / (1.f + __expf(-2.f * v)) - 1.f; }

// fp32 -> bf16 round-to-nearest-even (the verified-correct conversion —
// v_cvt_pk_bf16_f32 regressed absmax 0.016 -> 0.141 in R2, do not use)
__device__ __forceinline__ unsigned short f2bf(float f) {
    unsigned int u = __float_as_uint(f);
    unsigned int r = (u + 0x7FFFu + ((u >> 16) & 1u)) >> 16;
    return (unsigned short)r;
}

// unpack a u32 holding 2 bf16 into a float2 {lo, hi}
__device__ __forceinline__ f32x2 unpk(unsigned int u) {
    f32x2 r;
    r[0] = __uint_as_float(u << 16);
    r[1] = __uint_as_float(u & 0xffff0000u);
    return r;
}

// load a zero-padded 3x3 patch of one channel plane (HxW) at (y,x)
__device__ __forceinline__ void load_patch(const float* __restrict__ xc, int y, int x, float* p) {
#pragma unroll
    for (int dy = -1; dy <= 1; dy++) {
#pragma unroll
        for (int dx = -1; dx <= 1; dx++) {
            int yy = y + dy, xx = x + dx;
            float v = (yy >= 0 && yy < H && xx >= 0 && xx < W) ? xc[yy * W + xx] : 0.f;
            p[(dy + 1) * 3 + (dx + 1)] = v;
        }
    }
}

// ---------------------------------------------------------------------------
// Prepack LSTM weights into M=192 A-fragments (12 M-tiles), bf16.
// ---------------------------------------------------------------------------
__global__ void k_prepL(const float* __restrict__ lw, unsigned short* __restrict__ aplk) {
    int g = blockIdx.x;            // M-tile 0..11
    int tid = threadIdx.x;         // 0..511
    int lane = tid >> 3, j = tid & 7;
    int o = g * 16 + (lane & 15);
    int k = ((lane >> 4) << 3) + j;
    float val = 0.f;
    if (k < 27) {
        int c = k / 9, tap = k % 9;
        int gate = o >> 6, nk = o & 63;
        int base = (gate == 0) ? 0 : (gate == 1) ? 2 * NK : 3 * NK;
        val = lw[(size_t)(base + nk) * (CIN * 9) + c * 9 + tap];
    }
    aplk[(size_t)g * 512 + tid] = f2bf(val);
}

// ---------------------------------------------------------------------------
// ConvLSTM as MFMA implicit GEMM. Also writes lrp (pixel-major lr channels)
// from wave 0 — fuses the former k_lr kernel.
// ---------------------------------------------------------------------------
__global__ __launch_bounds__(256, 4) void k_lstm(const float* __restrict__ X,
                                                 const unsigned short* __restrict__ aplk,
                                                 const float* __restrict__ lb,
                                                 unsigned short* __restrict__ xcatA,
                                                 float* __restrict__ hid_out,
                                                 float* __restrict__ cell_out,
                                                 float* __restrict__ lrp) {
    int tid = threadIdx.x;
    int lane = tid & 63;
    int nt = __builtin_amdgcn_readfirstlane(tid >> 6);
    int blk = blockIdx.x;
    int sg = (blk & 7) * 128 + (blk >> 3);
    int b = sg >> 8;
    int hwbase = (sg & 255) * 64;
    int n = lane & 15, q = lane >> 4;
    int hw = hwbase + nt * 16 + n;
    int y = hw >> 7, x = hw & (W - 1);

    // fused k_lr: wave 0 writes the pixel-major lr channels for this block's 64 px
    if (nt == 0) {
        int px = hwbase + lane;
        f32x4 v = {X[(size_t)(b * NC + 0) * HW + px], X[(size_t)(b * NC + 1) * HW + px],
                   X[(size_t)(b * NC + 2) * HW + px], 0.f};
        *(f32x4*)(lrp + ((size_t)b * HW + px) * 4) = v;
    }

    // B-fragment: 8 patch samples, k = q*8+j
    bf16x8 bf;
#pragma unroll
    for (int j = 0; j < 8; j++) {
        int k = q * 8 + j;
        float v = 0.f;
        if (k < 27) {
            int c = k / 9, tap = k % 9;
            int ky = tap / 3, kx = tap % 3;
            int yy = y + ky - 1, xx = x + kx - 1;
            if (yy >= 0 && yy < H && xx >= 0 && xx < W)
                v = X[(size_t)(b * NC + c) * HW + yy * W + xx];
        }
        bf[j] = (short)f2bf(v);
    }

    f32x4 acc[12];
#pragma unroll
    for (int mt = 0; mt < 12; mt++) { f32x4 z = {0.f, 0.f, 0.f, 0.f}; acc[mt] = z; }
#pragma unroll
    for (int mt = 0; mt < 12; mt++) {
        bf16x8 af = *(const bf16x8*)(aplk + (size_t)mt * 512 + lane * 8);
        acc[mt] = __builtin_amdgcn_mfma_f32_16x16x32_bf16(af, bf, acc[mt], 0, 0, 0);
    }

    unsigned short* xo = xcatA + ((size_t)b * HW + hw) * CST;
#pragma unroll
    for (int mt = 0; mt < 4; mt++) {
        float hv4[4];
#pragma unroll
        for (int r = 0; r < 4; r++) {
            int nk = mt * 16 + q * 4 + r;
            float gi = acc[mt][r] + lb[nk];
            float go = acc[mt + 4][r] + lb[2 * NK + nk];
            float gg = acc[mt + 8][r] + lb[3 * NK + nk];
            float cv = fast_sigmoid(gi) * fast_tanh(gg);
            float hv = fast_sigmoid(go) * fast_tanh(cv);
            hv4[r] = hv;
            hid_out[(size_t)(b * NK + nk) * HW + hw] = hv;
            cell_out[(size_t)(b * NK + nk) * HW + hw] = cv;
        }
        u32x2 st;
        st[0] = (unsigned int)f2bf(hv4[0]) | ((unsigned int)f2bf(hv4[1]) << 16);
        st[1] = (unsigned int)f2bf(hv4[2]) | ((unsigned int)f2bf(hv4[3]) << 16);
        *(u32x2*)(xo + mt * 16 + q * 4) = st;
    }
}

// ---------------------------------------------------------------------------
// Prepack deform weights dw[o<64][c<67][k<9] into MFMA A-fragment order, bf16.
// ---------------------------------------------------------------------------
__global__ void k_prepA(const float* __restrict__ w, unsigned short* __restrict__ apk) {
    int g = blockIdx.x;            // (tap*3+ks)*4+mt
    int tid = threadIdx.x;         // 0..511
    int lane = tid >> 3, j = tid & 7;
    int mt = g & 3, r = g >> 2;    // r = tap*3+ks
    int ks = r % 3, tap = r / 3;
    int o = mt * 16 + (lane & 15);
    int c = ks * 32 + ((lane >> 4) << 3) + j;
    float val = (c < CIN) ? w[(size_t)o * (CIN * 9) + c * 9 + tap] : 0.f;
    apk[(size_t)g * 512 + tid] = f2bf(val);
}

// Prepack offset(18)+mask(9) conv weights into M=32 A-fragments, bf16.
__global__ void k_prepOM(const float* __restrict__ ow, const float* __restrict__ mw,
                         unsigned short* __restrict__ apk) {
    int g = blockIdx.x;            // (tap*3+kss)*2+mt
    int tid = threadIdx.x;         // 0..511
    int lane = tid >> 3, j = tid & 7;
    int mt = g & 1, r = g >> 1;    // r = tap*3+kss
    int kss = r % 3, tap = r / 3;
    int o = mt * 16 + (lane & 15);
    int c = kss * 32 + ((lane >> 4) << 3) + j;
    float val = 0.f;
    if (c < CIN) {
        if (o < 18) val = ow[(size_t)o * (CIN * 9) + c * 9 + tap];
        else if (o < 27) val = mw[(size_t)(o - 18) * (CIN * 9) + c * 9 + tap];
    }
    apk[(size_t)g * 512 + tid] = f2bf(val);
}

// ---------------------------------------------------------------------------
// FUSED offset/mask conv + deformable conv — wave-independent, 2-deep
// software-pipelined with NAMED double-buffer structs (pA/pB) and a fully
// explicit issue/consume call sequence: no runtime-indexed arrays anywhere
// (R4's d[2][2] arrays went to scratch: WRITE_SIZE 8->59 MB — rule #20).
// Phase 2 stages ks0 fragments + coeffs at issue; ks1 + lr loads issue at
// consume top (covered by ks0 blend + MFMAs). Arithmetic identical to R3.
// ---------------------------------------------------------------------------
__global__ __launch_bounds__(256, 4) void k_offdef(const unsigned short* __restrict__ xcat,
                                                   const float* __restrict__ lrp,
                                                   const unsigned short* __restrict__ apkom,
                                                   const float* __restrict__ ob,
                                                   const float* __restrict__ mb,
                                                   const unsigned short* __restrict__ apk,
                                                   const float* __restrict__ bias,
                                                   unsigned short* __restrict__ xout) {
    __shared__ float somp[4][16][37];   // 9472 B; stride 37: conflict-free reads
    int tid = threadIdx.x;
    int lane = tid & 63;
    int wid = __builtin_amdgcn_readfirstlane(tid >> 6);
    int blk = blockIdx.x;                    // 0..1023
    int sg = (blk & 7) * 128 + (blk >> 3);   // XCD-contiguous strip id
    int b = sg >> 8;
    int hwbase = (sg & 255) * 64;
    int n = lane & 15, q = lane >> 4;
    int hw = hwbase + wid * 16 + n;
    int y = hw >> 7, x = hw & (W - 1);

    const unsigned short* xb = xcat + (size_t)b * HW * CST;
    const float* lb_ = lrp + (size_t)b * HW * 4;

    // ---------------- phase 1: offset+mask conv, 2-deep pipelined ---------
    {
        f32x4 acc2[2];
#pragma unroll
        for (int mt = 0; mt < 2; mt++) { f32x4 z = {0.f, 0.f, 0.f, 0.f}; acc2[mt] = z; }

        struct P1B { u32x4 d0, d1; int ii; bool v; };
        P1B pA, pB;

        auto p1_issue = [&](int tap, P1B& bb) {
            int ky = tap / 3, kx = tap - ky * 3;
            int yy = y + ky - 1, xx = x + kx - 1;
            bb.v = (yy >= 0 && yy < H && xx >= 0 && xx < W);
            bb.ii = min(max(yy, 0), H - 1) * W + min(max(xx, 0), W - 1);
            const unsigned short* xr = xb + ((size_t)bb.ii << 6);
            bb.d0 = *(const u32x4*)(xr + q * 8);
            bb.d1 = *(const u32x4*)(xr + 32 + q * 8);
        };
        auto p1_cons = [&](int tap, P1B& bb) {
            const unsigned short* ab = apkom + (size_t)(tap * 6) * 512 + lane * 8;
            bool vld = bb.v;
            f32x4 L = {0.f, 0.f, 0.f, 0.f};
            if (q == 0 && vld) L = *(const f32x4*)(lb_ + ((size_t)bb.ii << 2));
            // kss = 0
            {
                bf16x8 bfv;
                if (vld) bfv = *(const bf16x8*)&bb.d0;
                else { bf16x8 z = {0, 0, 0, 0, 0, 0, 0, 0}; bfv = z; }
#pragma unroll
                for (int mt = 0; mt < 2; mt++) {
                    bf16x8 af = *(const bf16x8*)(ab + (size_t)(0 * 2 + mt) * 512);
                    acc2[mt] = __builtin_amdgcn_mfma_f32_16x16x32_bf16(af, bfv, acc2[mt], 0, 0, 0);
                }
            }
            // kss = 1
            {
                bf16x8 bfv;
                if (vld) bfv = *(const bf16x8*)&bb.d1;
                else { bf16x8 z = {0, 0, 0, 0, 0, 0, 0, 0}; bfv = z; }
#pragma unroll
                for (int mt = 0; mt < 2; mt++) {
                    bf16x8 af = *(const bf16x8*)(ab + (size_t)(1 * 2 + mt) * 512);
                    acc2[mt] = __builtin_amdgcn_mfma_f32_16x16x32_bf16(af, bfv, acc2[mt], 0, 0, 0);
                }
            }
            // kss = 2: lr channels (q==0 lanes)
            bf16x8 bf2 = {0, 0, 0, 0, 0, 0, 0, 0};
            if (q == 0 && vld) {
#pragma unroll
                for (int j = 0; j < 4; j++) bf2[j] = (short)f2bf(L[j]);
            }
#pragma unroll
            for (int mt = 0; mt < 2; mt++) {
                bf16x8 af = *(const bf16x8*)(ab + (size_t)(4 + mt) * 512);
                acc2[mt] = __builtin_amdgcn_mfma_f32_16x16x32_bf16(af, bf2, acc2[mt], 0, 0, 0);
            }
        };

        p1_issue(0, pA);
        p1_issue(1, pB); p1_cons(0, pA);
        p1_issue(2, pA); p1_cons(1, pB);
        p1_issue(3, pB); p1_cons(2, pA);
        p1_issue(4, pA); p1_cons(3, pB);
        p1_issue(5, pB); p1_cons(4, pA);
        p1_issue(6, pA); p1_cons(5, pB);
        p1_issue(7, pB); p1_cons(6, pA);
        p1_issue(8, pA); p1_cons(7, pB);
        p1_cons(8, pA);

        // LDS transpose: lane (n,q) holds o = mt*16+q*4+r for pixel n
#pragma unroll
        for (int mt = 0; mt < 2; mt++)
#pragma unroll
            for (int r = 0; r < 4; r++) {
                int o = mt * 16 + q * 4 + r;
                float s = acc2[mt][r];
                if (o < 18)
                    somp[wid][n][(o >> 1) * 4 + (o & 1)] = s + ob[o];
                else if (o < 27)
                    somp[wid][n][(o - 18) * 4 + 2] = 2.f * fast_sigmoid(s + mb[o - 18]);
            }
    }
    __syncthreads();

    // ---------------- phase 2: deformable conv, 2-deep pipelined ----------
    f32x4 acc[4];
#pragma unroll
    for (int mt = 0; mt < 4; mt++) { f32x4 z = {0.f, 0.f, 0.f, 0.f}; acc[mt] = z; }

    struct P2B {
        float a00, a01, a10, a11;
        int j00, j01, j10, j11;
        u32x4 d00, d01, d10, d11;   // ks0 fragments
    };
    P2B bA, bB;

    auto p2_issue = [&](int tap, P2B& bb) {
        float omy = somp[wid][n][tap * 4 + 0];
        float omx = somp[wid][n][tap * 4 + 1];
        float m = somp[wid][n][tap * 4 + 2];
        int ky = tap / 3, kx = tap - ky * 3;
        float py = (float)(y + ky - 1) + omy;
        float px_ = (float)(x + kx - 1) + omx;
        float fy = floorf(py), fx = floorf(px_);
        float wy = py - fy, wx = px_ - fx;
        int y0 = (int)fy, x0 = (int)fx;
        int y1 = y0 + 1, x1 = x0 + 1;
        float vy0 = (y0 >= 0 && y0 <= H - 1) ? 1.f : 0.f;
        float vy1 = (y1 >= 0 && y1 <= H - 1) ? 1.f : 0.f;
        float vx0 = (x0 >= 0 && x0 <= W - 1) ? 1.f : 0.f;
        float vx1 = (x1 >= 0 && x1 <= W - 1) ? 1.f : 0.f;
        int yc0 = min(max(y0, 0), H - 1), yc1 = min(max(y1, 0), H - 1);
        int xc0 = min(max(x0, 0), W - 1), xc1 = min(max(x1, 0), W - 1);
        bb.a00 = (1.f - wy) * (1.f - wx) * m * vy0 * vx0;
        bb.a01 = (1.f - wy) * wx * m * vy0 * vx1;
        bb.a10 = wy * (1.f - wx) * m * vy1 * vx0;
        bb.a11 = wy * wx * m * vy1 * vx1;
        bb.j00 = yc0 * W + xc0; bb.j01 = yc0 * W + xc1;
        bb.j10 = yc1 * W + xc0; bb.j11 = yc1 * W + xc1;
        int c0 = q * 8;
        bb.d00 = *(const u32x4*)(xb + ((size_t)bb.j00 << 6) + c0);
        bb.d01 = *(const u32x4*)(xb + ((size_t)bb.j01 << 6) + c0);
        bb.d10 = *(const u32x4*)(xb + ((size_t)bb.j10 << 6) + c0);
        bb.d11 = *(const u32x4*)(xb + ((size_t)bb.j11 << 6) + c0);
    };

    auto p2_cons = [&](int tap, P2B& bb) {
        const unsigned short* ab = apk + (size_t)(tap * 12) * 512 + lane * 8;
        float a00 = bb.a00, a01 = bb.a01, a10 = bb.a10, a11 = bb.a11;
        // issue ks1 + lr loads up front; consumed after ks0 blend + MFMAs
        int c1 = 32 + q * 8;
        u32x4 e00 = *(const u32x4*)(xb + ((size_t)bb.j00 << 6) + c1);
        u32x4 e01 = *(const u32x4*)(xb + ((size_t)bb.j01 << 6) + c1);
        u32x4 e10 = *(const u32x4*)(xb + ((size_t)bb.j10 << 6) + c1);
        u32x4 e11 = *(const u32x4*)(xb + ((size_t)bb.j11 << 6) + c1);
        f32x4 L00, L01, L10, L11;
        if (q == 0) {
            L00 = *(const f32x4*)(lb_ + ((size_t)bb.j00 << 2));
            L01 = *(const f32x4*)(lb_ + ((size_t)bb.j01 << 2));
            L10 = *(const f32x4*)(lb_ + ((size_t)bb.j10 << 2));
            L11 = *(const f32x4*)(lb_ + ((size_t)bb.j11 << 2));
        }
        // ks = 0 (staged)
        {
            bf16x8 bf;
            unsigned int* bfu = (unsigned int*)&bf;
#pragma unroll
            for (int e = 0; e < 4; e++) {
                f32x2 v = unpk(bb.d00[e]) * a00 + unpk(bb.d01[e]) * a01
                        + unpk(bb.d10[e]) * a10 + unpk(bb.d11[e]) * a11;
                bfu[e] = (unsigned int)f2bf(v[0]) | ((unsigned int)f2bf(v[1]) << 16);
            }
#pragma unroll
            for (int mt = 0; mt < 4; mt++) {
                bf16x8 af = *(const bf16x8*)(ab + (size_t)(0 * 4 + mt) * 512);
                acc[mt] = __builtin_amdgcn_mfma_f32_16x16x32_bf16(af, bf, acc[mt], 0, 0, 0);
            }
        }
        // ks = 1 (loaded this step)
        {
            bf16x8 bf;
            unsigned int* bfu = (unsigned int*)&bf;
#pragma unroll
            for (int e = 0; e < 4; e++) {
                f32x2 v = unpk(e00[e]) * a00 + unpk(e01[e]) * a01
                        + unpk(e10[e]) * a10 + unpk(e11[e]) * a11;
                bfu[e] = (unsigned int)f2bf(v[0]) | ((unsigned int)f2bf(v[1]) << 16);
            }
#pragma unroll
            for (int mt = 0; mt < 4; mt++) {
                bf16x8 af = *(const bf16x8*)(ab + (size_t)(1 * 4 + mt) * 512);
                acc[mt] = __builtin_amdgcn_mfma_f32_16x16x32_bf16(af, bf, acc[mt], 0, 0, 0);
            }
        }
        // ks = 2: lr channels via q==0 lanes
        bf16x8 bf2 = {0, 0, 0, 0, 0, 0, 0, 0};
        if (q == 0) {
            f32x4 Lv = L00 * a00 + L01 * a01 + L10 * a10 + L11 * a11;
#pragma unroll
            for (int j = 0; j < 4; j++) bf2[j] = (short)f2bf(Lv[j]);
        }
#pragma unroll
        for (int mt = 0; mt < 4; mt++) {
            bf16x8 af = *(const bf16x8*)(ab + (size_t)(2 * 4 + mt) * 512);
            acc[mt] = __builtin_amdgcn_mfma_f32_16x16x32_bf16(af, bf2, acc[mt], 0, 0, 0);
        }
    };

    p2_issue(0, bA);
    p2_issue(1, bB); p2_cons(0, bA);
    p2_issue(2, bA); p2_cons(1, bB);
    p2_issue(3, bB); p2_cons(2, bA);
    p2_issue(4, bA); p2_cons(3, bB);
    p2_issue(5, bB); p2_cons(4, bA);
    p2_issue(6, bA); p2_cons(5, bB);
    p2_issue(7, bB); p2_cons(6, bA);
    p2_issue(8, bA); p2_cons(7, bB);
    p2_cons(8, bA);

    // direct epilogue: lane (n,q) stores o = mt*16+q*4+r for its pixel
    unsigned short* xo = xout + ((size_t)b * HW + hw) * CST;
#pragma unroll
    for (int mt = 0; mt < 4; mt++) {
        float s[4];
#pragma unroll
        for (int r = 0; r < 4; r++) {
            int o = mt * 16 + q * 4 + r;
            s[r] = acc[mt][r] + bias[o];
        }
        u32x2 st;
        st[0] = (unsigned int)f2bf(s[0]) | ((unsigned int)f2bf(s[1]) << 16);
        st[1] = (unsigned int)f2bf(s[2]) | ((unsigned int)f2bf(s[3]) << 16);
        *(u32x2*)(xo + mt * 16 + q * 4) = st;
    }
}

// ---------------------------------------------------------------------------
// Final 3-channel conv, tap-split across 4 waves with LDS reduction.
// ---------------------------------------------------------------------------
__global__ __launch_bounds__(256, 4) void k_conv3(const unsigned short* __restrict__ xcat,
                                                  const float* __restrict__ lrp,
                                                  const float* __restrict__ cw,
                                                  const float* __restrict__ cb,
                                                  float* __restrict__ y3) {
    __shared__ float red[4 * 3 * 64];  // 3072 B
    int tid = threadIdx.x;
    int lane = tid & 63;
    int wid = __builtin_amdgcn_readfirstlane(tid >> 6);
    int blk = blockIdx.x;
    int sg = (blk & 7) * 128 + (blk >> 3);
    int b = sg >> 8;
    int hwbase = (sg & 255) * 64;
    int hw = hwbase + lane;
    int y = hw >> 7, x = hw & (W - 1);
    int t0 = (wid == 0) ? 0 : 3 + (wid - 1) * 2;
    int t1 = (wid == 0) ? 3 : t0 + 2;

    float a0 = 0.f, a1 = 0.f, a2 = 0.f;
    const unsigned short* xb = xcat + (size_t)b * HW * CST;
    const float* lb_ = lrp + (size_t)b * HW * 4;
#pragma unroll 1
    for (int tap = t0; tap < t1; tap++) {
        int ky = tap / 3, kx = tap - ky * 3;
        int yy = y + ky - 1, xx = x + kx - 1;
        if (yy < 0 || yy >= H || xx < 0 || xx >= W) continue;
        int ii = yy * W + xx;
        const unsigned short* xr = xb + ((size_t)ii << 6);
#pragma unroll
        for (int c8 = 0; c8 < 8; c8++) {
            u32x4 d = *(const u32x4*)(xr + c8 * 8);
#pragma unroll
            for (int e = 0; e < 4; e++) {
                int c = c8 * 8 + e * 2;
                float lo = __uint_as_float(d[e] << 16);
                float hi = __uint_as_float(d[e] & 0xffff0000u);
                a0 += lo * cw[0 * (CIN * 9) + c * 9 + tap] + hi * cw[0 * (CIN * 9) + (c + 1) * 9 + tap];
                a1 += lo * cw[1 * (CIN * 9) + c * 9 + tap] + hi * cw[1 * (CIN * 9) + (c + 1) * 9 + tap];
                a2 += lo * cw[2 * (CIN * 9) + c * 9 + tap] + hi * cw[2 * (CIN * 9) + (c + 1) * 9 + tap];
            }
        }
        f32x4 L = *(const f32x4*)(lb_ + ((size_t)ii << 2));
#pragma unroll
        for (int e = 0; e < 3; e++) {
            a0 += L[e] * cw[0 * (CIN * 9) + (64 + e) * 9 + tap];
            a1 += L[e] * cw[1 * (CIN * 9) + (64 + e) * 9 + tap];
            a2 += L[e] * cw[2 * (CIN * 9) + (64 + e) * 9 + tap];
        }
    }
    red[(wid * 3 + 0) * 64 + lane] = a0;
    red[(wid * 3 + 1) * 64 + lane] = a1;
    red[(wid * 3 + 2) * 64 + lane] = a2;
    __syncthreads();
    if (tid < 192) {
        int oc = tid >> 6, px = tid & 63;
        float s = red[(0 * 3 + oc) * 64 + px] + red[(1 * 3 + oc) * 64 + px]
                + red[(2 * 3 + oc) * 64 + px] + red[(3 * 3 + oc) * 64 + px];
        y3[(size_t)(b * NC + oc) * HW + hwbase + px] = s + cb[oc];
    }
}

// global average pool: one block per (b,c)
__global__ __launch_bounds__(256) void k_pool(const float* __restrict__ y3,
                                              float* __restrict__ pooled) {
    int bc = blockIdx.x;  // 0..11
    const float* p = y3 + (size_t)bc * HW;
    float s = 0.f;
    for (int i = threadIdx.x; i < HW; i += 256) s += p[i];
    __shared__ float red[256];
    red[threadIdx.x] = s;
    __syncthreads();
    for (int off = 128; off > 0; off >>= 1) {
        if (threadIdx.x < off) red[threadIdx.x] += red[threadIdx.x + off];
        __syncthreads();
    }
    if (threadIdx.x == 0) pooled[bc] = red[0] / (float)HW;
}

// ---------------------------------------------------------------------------
// Fused DDF upsample: spatial conv + dynamic combine + pixel_shuffle + clip.
// Computes the tiny per-branch channel MLP in-block (fused k_ch).
// ---------------------------------------------------------------------------
__global__ __launch_bounds__(256) void k_ddf(const float* __restrict__ y3,
                                             const float* __restrict__ spw,
                                             const float* __restrict__ spb,
                                             const float* __restrict__ pooled,
                                             const float* __restrict__ ch_w1,
                                             const float* __restrict__ ch_b1,
                                             const float* __restrict__ ch_w2,
                                             const float* __restrict__ ch_b2,
                                             float* __restrict__ out) {
    __shared__ float s_spw[4 * K2 * NC * 9];  // 972
    __shared__ float s_spb[4 * K2];           // 36
    __shared__ float s_ch[4 * NC * K2];       // 108
    int t = blockIdx.x * blockDim.x + threadIdx.x;
    int b = t >> 14, hw = t & (HW - 1), y = hw >> 7, x = hw & (W - 1);
    int s0 = blockIdx.y * 4;
    for (int i = threadIdx.x; i < 4 * K2 * NC * 9; i += 256) s_spw[i] = spw[s0 * K2 * NC * 9 + i];
    if (threadIdx.x < 4 * K2) s_spb[threadIdx.x] = spb[s0 * K2 + threadIdx.x];
    if (threadIdx.x < 4 * NC * K2) {
        int t2 = threadIdx.x;
        int si = t2 / (NC * K2), kk = t2 - si * (NC * K2);
        int s = s0 + si;
        float a = ch_b2[s * (NC * K2) + kk];
#pragma unroll
        for (int m = 0; m < MID; m++) {
            float h1 = ch_b1[s * MID + m];
#pragma unroll
            for (int c = 0; c < NC; c++) h1 += pooled[b * NC + c] * ch_w1[(s * MID + m) * NC + c];
            a += fmaxf(h1, 0.f) * ch_w2[(s * (NC * K2) + kk) * MID + m];
        }
        s_ch[t2] = a;
    }
    __syncthreads();
    float p[NC][9];
#pragma unroll
    for (int c = 0; c < NC; c++) load_patch(y3 + (b * NC + c) * HW, y, x, p[c]);
#pragma unroll
    for (int si = 0; si < 4; si++) {
        int s = s0 + si;
        float spv[K2];
#pragma unroll
        for (int k = 0; k < K2; k++) {
            float a = s_spb[si * K2 + k];
            const float* w = s_spw + (si * K2 + k) * (NC * 9);
#pragma unroll
            for (int c = 0; c < NC; c++)
#pragma unroll
                for (int tt = 0; tt < 9; tt++) a += p[c][tt] * w[c * 9 + tt];
            spv[k] = a;
        }
        int sy = s >> 2, sx = s & 3;
#pragma unroll
        for (int c = 0; c < NC; c++) {
            float a = 0.f;
            const float* chp = s_ch + (si * NC + c) * K2;
#pragma unroll
            for (int k = 0; k < K2; k++) a += p[c][k] * (chp[k] + spv[k]);
            a = fminf(fmaxf(a, 0.f), 255.f);
            out[((size_t)(b * NC + c) * OUT_HW + (y * SCALE + sy)) * OUT_HW + (x * SCALE + sx)] = a;
        }
    }
}

extern "C" void kernel_launch(void* const* d_in, const int* in_sizes, int n_in,
                              void* d_out, int out_size, void* d_ws, size_t ws_size,
                              hipStream_t stream) {
    const float* X = (const float*)d_in[0];
    const float* lstm_w = (const float*)d_in[1];
    const float* lstm_b = (const float*)d_in[2];
    const float* ow[3] = {(const float*)d_in[3], (const float*)d_in[9], (const float*)d_in[15]};
    const float* ob[3] = {(const float*)d_in[4], (const float*)d_in[10], (const float*)d_in[16]};
    const float* mw[3] = {(const float*)d_in[5], (const float*)d_in[11], (const float*)d_in[17]};
    const float* mb[3] = {(const float*)d_in[6], (const float*)d_in[12], (const float*)d_in[18]};
    const float* dw[3] = {(const float*)d_in[7], (const float*)d_in[13], (const float*)d_in[19]};
    const float* db[3] = {(const float*)d_in[8], (const float*)d_in[14], (const float*)d_in[20]};
    const float* conv_w = (const float*)d_in[21];
    const float* conv_b = (const float*)d_in[22];
    const float* sp_w = (const float*)d_in[23];
    const float* sp_b = (const float*)d_in[24];
    const float* ch_w1 = (const float*)d_in[25];
    const float* ch_b1 = (const float*)d_in[26];
    const float* ch_w2 = (const float*)d_in[27];
    const float* ch_b2 = (const float*)d_in[28];

    float* out = (float*)d_out;
    const size_t OUT_IMG = (size_t)B * NC * OUT_HW * OUT_HW;  // 3145728
    const size_t HIDSZ = (size_t)B * NK * HW;                 // 4194304
    float* hid_out = out + OUT_IMG;
    float* cell_out = out + OUT_IMG + HIDSZ;

    float* ws = (float*)d_ws;
    const size_t XCATF = (size_t)B * HW * CST / 2;  // bf16 xcat, in float units
    unsigned short* xcatA = (unsigned short*)ws;  ws += XCATF;
    unsigned short* xcatB = (unsigned short*)ws;  ws += XCATF;
    float* lrp = ws;              ws += (size_t)B * HW * 4;
    unsigned short* apk[3];
    for (int i = 0; i < 3; i++) { apk[i] = (unsigned short*)ws; ws += 108 * 512 / 2; }
    unsigned short* apkOM[3];
    for (int i = 0; i < 3; i++) { apkOM[i] = (unsigned short*)ws; ws += 54 * 512 / 2; }
    unsigned short* aplk = (unsigned short*)ws;  ws += 12 * 512 / 2;
    float* y3 = ws;               ws += (size_t)B * NC * HW;
    float* pooled = ws;           ws += 16;

    dim3 blk(256);
    dim3 g4(B * HW / 256, 4);
    dim3 gd(B * HW / 64);         // 1024 strips (64 px per block, 16 per wave)

    k_prepL<<<dim3(12), dim3(512), 0, stream>>>(lstm_w, aplk);
    for (int i = 0; i < 3; i++) {
        k_prepA<<<dim3(108), dim3(512), 0, stream>>>(dw[i], apk[i]);
        k_prepOM<<<dim3(54), dim3(512), 0, stream>>>(ow[i], mw[i], apkOM[i]);
    }
    k_lstm<<<gd, blk, 0, stream>>>(X, aplk, lstm_b, xcatA, hid_out, cell_out, lrp);

    // layer 1: xcatA -> xcatB (offmask fused into deform, pipelined)
    k_offdef<<<gd, blk, 0, stream>>>(xcatA, lrp, apkOM[0], ob[0], mb[0], apk[0], db[0], xcatB);
    // layer 2: xcatB -> xcatA
    k_offdef<<<gd, blk, 0, stream>>>(xcatB, lrp, apkOM[1], ob[1], mb[1], apk[1], db[1], xcatA);
    // layer 3: xcatA -> xcatB
    k_offdef<<<gd, blk, 0, stream>>>(xcatA, lrp, apkOM[2], ob[2], mb[2], apk[2], db[2], xcatB);

    k_conv3<<<gd, blk, 0, stream>>>(xcatB, lrp, conv_w, conv_b, y3);
    k_pool<<<dim3(B * NC), blk, 0, stream>>>(y3, pooled);
    k_ddf<<<g4, blk, 0, stream>>>(y3, sp_w, sp_b, pooled, ch_w1, ch_b1, ch_w2, ch_b2, out);
}

// Round 6
// 330.984 us; speedup vs baseline: 1.3391x; 1.2344x over previous
//
#include <hip/hip_runtime.h>
#include <hip/hip_bf16.h>
#include <math.h>

// Problem constants
#define NC 3
#define NK 64
#define KK 3
#define K2 9
#define PAD 1
#define SCALE 4
#define S2 16
#define MID 4
#define B 4
#define H 128
#define W 128
#define HW (H*W)          // 16384
#define CIN 67            // NK + NC
#define OUT_HW (H*SCALE)  // 512
#define CST 64            // xcat: 64 bf16 per pixel, stored PLANE-MAJOR:
                          // [8 planes][HW][8ch] — plane p holds ch p*8..p*8+8
                          // (16 B per pixel per plane; consecutive pixels
                          // contiguous -> coalesced lane runs)

typedef short bf16x8 __attribute__((ext_vector_type(8)));
typedef float f32x4 __attribute__((ext_vector_type(4)));
typedef float f32x2 __attribute__((ext_vector_type(2)));
typedef unsigned int u32x4 __attribute__((ext_vector_type(4)));
typedef unsigned int u32x2 __attribute__((ext_vector_type(2)));

__device__ __forceinline__ float fast_sigmoid(float v) { return 1.f / (1.f + __expf(-v)); }
__device__ __forceinline__ float fast_tanh(float v) { return 2.f / (1.f + __expf(-2.f * v)) - 1.f; }

// fp32 -> bf16 round-to-nearest-even (the verified-correct conversion —
// v_cvt_pk_bf16_f32 regressed absmax 0.016 -> 0.141 in R2, do not use)
__device__ __forceinline__ unsigned short f2bf(float f) {
    unsigned int u = __float_as_uint(f);
    unsigned int r = (u + 0x7FFFu + ((u >> 16) & 1u)) >> 16;
    return (unsigned short)r;
}

// unpack a u32 holding 2 bf16 into a float2 {lo, hi}
__device__ __forceinline__ f32x2 unpk(unsigned int u) {
    f32x2 r;
    r[0] = __uint_as_float(u << 16);
    r[1] = __uint_as_float(u & 0xffff0000u);
    return r;
}

// load a zero-padded 3x3 patch of one channel plane (HxW) at (y,x)
__device__ __forceinline__ void load_patch(const float* __restrict__ xc, int y, int x, float* p) {
#pragma unroll
    for (int dy = -1; dy <= 1; dy++) {
#pragma unroll
        for (int dx = -1; dx <= 1; dx++) {
            int yy = y + dy, xx = x + dx;
            float v = (yy >= 0 && yy < H && xx >= 0 && xx < W) ? xc[yy * W + xx] : 0.f;
            p[(dy + 1) * 3 + (dx + 1)] = v;
        }
    }
}

// ---------------------------------------------------------------------------
// Prepack LSTM weights into M=192 A-fragments (12 M-tiles), bf16.
// ---------------------------------------------------------------------------
__global__ void k_prepL(const float* __restrict__ lw, unsigned short* __restrict__ aplk) {
    int g = blockIdx.x;            // M-tile 0..11
    int tid = threadIdx.x;         // 0..511
    int lane = tid >> 3, j = tid & 7;
    int o = g * 16 + (lane & 15);
    int k = ((lane >> 4) << 3) + j;
    float val = 0.f;
    if (k < 27) {
        int c = k / 9, tap = k % 9;
        int gate = o >> 6, nk = o & 63;
        int base = (gate == 0) ? 0 : (gate == 1) ? 2 * NK : 3 * NK;
        val = lw[(size_t)(base + nk) * (CIN * 9) + c * 9 + tap];
    }
    aplk[(size_t)g * 512 + tid] = f2bf(val);
}

// ---------------------------------------------------------------------------
// ConvLSTM as MFMA implicit GEMM. Also writes lrp (pixel-major lr channels)
// from wave 0 — fuses the former k_lr kernel. xcat written plane-major.
// ---------------------------------------------------------------------------
__global__ __launch_bounds__(256, 4) void k_lstm(const float* __restrict__ X,
                                                 const unsigned short* __restrict__ aplk,
                                                 const float* __restrict__ lb,
                                                 unsigned short* __restrict__ xcatA,
                                                 float* __restrict__ hid_out,
                                                 float* __restrict__ cell_out,
                                                 float* __restrict__ lrp) {
    int tid = threadIdx.x;
    int lane = tid & 63;
    int nt = __builtin_amdgcn_readfirstlane(tid >> 6);
    int blk = blockIdx.x;
    int sg = (blk & 7) * 128 + (blk >> 3);
    int b = sg >> 8;
    int hwbase = (sg & 255) * 64;
    int n = lane & 15, q = lane >> 4;
    int hw = hwbase + nt * 16 + n;
    int y = hw >> 7, x = hw & (W - 1);

    // fused k_lr: wave 0 writes the pixel-major lr channels for this block's 64 px
    if (nt == 0) {
        int px = hwbase + lane;
        f32x4 v = {X[(size_t)(b * NC + 0) * HW + px], X[(size_t)(b * NC + 1) * HW + px],
                   X[(size_t)(b * NC + 2) * HW + px], 0.f};
        *(f32x4*)(lrp + ((size_t)b * HW + px) * 4) = v;
    }

    // B-fragment: 8 patch samples, k = q*8+j
    bf16x8 bf;
#pragma unroll
    for (int j = 0; j < 8; j++) {
        int k = q * 8 + j;
        float v = 0.f;
        if (k < 27) {
            int c = k / 9, tap = k % 9;
            int ky = tap / 3, kx = tap % 3;
            int yy = y + ky - 1, xx = x + kx - 1;
            if (yy >= 0 && yy < H && xx >= 0 && xx < W)
                v = X[(size_t)(b * NC + c) * HW + yy * W + xx];
        }
        bf[j] = (short)f2bf(v);
    }

    f32x4 acc[12];
#pragma unroll
    for (int mt = 0; mt < 12; mt++) { f32x4 z = {0.f, 0.f, 0.f, 0.f}; acc[mt] = z; }
#pragma unroll
    for (int mt = 0; mt < 12; mt++) {
        bf16x8 af = *(const bf16x8*)(aplk + (size_t)mt * 512 + lane * 8);
        acc[mt] = __builtin_amdgcn_mfma_f32_16x16x32_bf16(af, bf, acc[mt], 0, 0, 0);
    }

    unsigned short* xo = xcatA + (size_t)b * HW * CST;   // batch base, plane-major
#pragma unroll
    for (int mt = 0; mt < 4; mt++) {
        float hv4[4];
#pragma unroll
        for (int r = 0; r < 4; r++) {
            int nk = mt * 16 + q * 4 + r;
            float gi = acc[mt][r] + lb[nk];
            float go = acc[mt + 4][r] + lb[2 * NK + nk];
            float gg = acc[mt + 8][r] + lb[3 * NK + nk];
            float cv = fast_sigmoid(gi) * fast_tanh(gg);
            float hv = fast_sigmoid(go) * fast_tanh(cv);
            hv4[r] = hv;
            hid_out[(size_t)(b * NK + nk) * HW + hw] = hv;
            cell_out[(size_t)(b * NK + nk) * HW + hw] = cv;
        }
        u32x2 st;
        st[0] = (unsigned int)f2bf(hv4[0]) | ((unsigned int)f2bf(hv4[1]) << 16);
        st[1] = (unsigned int)f2bf(hv4[2]) | ((unsigned int)f2bf(hv4[3]) << 16);
        // plane p = 2*mt + (q>>1); channel offset (q&1)*4
        int p = 2 * mt + (q >> 1);
        *(u32x2*)(xo + (((size_t)p * HW + hw) << 3) + (q & 1) * 4) = st;
    }
}

// ---------------------------------------------------------------------------
// Prepack deform weights dw[o<64][c<67][k<9] into MFMA A-fragment order, bf16.
// ---------------------------------------------------------------------------
__global__ void k_prepA(const float* __restrict__ w, unsigned short* __restrict__ apk) {
    int g = blockIdx.x;            // (tap*3+ks)*4+mt
    int tid = threadIdx.x;         // 0..511
    int lane = tid >> 3, j = tid & 7;
    int mt = g & 3, r = g >> 2;    // r = tap*3+ks
    int ks = r % 3, tap = r / 3;
    int o = mt * 16 + (lane & 15);
    int c = ks * 32 + ((lane >> 4) << 3) + j;
    float val = (c < CIN) ? w[(size_t)o * (CIN * 9) + c * 9 + tap] : 0.f;
    apk[(size_t)g * 512 + tid] = f2bf(val);
}

// Prepack offset(18)+mask(9) conv weights into M=32 A-fragments, bf16.
__global__ void k_prepOM(const float* __restrict__ ow, const float* __restrict__ mw,
                         unsigned short* __restrict__ apk) {
    int g = blockIdx.x;            // (tap*3+kss)*2+mt
    int tid = threadIdx.x;         // 0..511
    int lane = tid >> 3, j = tid & 7;
    int mt = g & 1, r = g >> 1;    // r = tap*3+kss
    int kss = r % 3, tap = r / 3;
    int o = mt * 16 + (lane & 15);
    int c = kss * 32 + ((lane >> 4) << 3) + j;
    float val = 0.f;
    if (c < CIN) {
        if (o < 18) val = ow[(size_t)o * (CIN * 9) + c * 9 + tap];
        else if (o < 27) val = mw[(size_t)(o - 18) * (CIN * 9) + c * 9 + tap];
    }
    apk[(size_t)g * 512 + tid] = f2bf(val);
}

// ---------------------------------------------------------------------------
// FUSED offset/mask conv + deformable conv — wave-independent (R3 structure,
// no manual pipelining: R4/R5 both spilled) over PLANE-MAJOR xcat.
// Lane (n,q) at ks reads plane ks*4+q at pixel j: consecutive lanes read
// consecutive 16B -> coalesced runs instead of 128B-stride scatters
// (the TA address-throughput bottleneck identified in R5 post-mortem).
// Arithmetic identical to verified R3.
// ---------------------------------------------------------------------------
__global__ __launch_bounds__(256, 4) void k_offdef(const unsigned short* __restrict__ xcat,
                                                   const float* __restrict__ lrp,
                                                   const unsigned short* __restrict__ apkom,
                                                   const float* __restrict__ ob,
                                                   const float* __restrict__ mb,
                                                   const unsigned short* __restrict__ apk,
                                                   const float* __restrict__ bias,
                                                   unsigned short* __restrict__ xout) {
    __shared__ float somp[4][16][37];   // 9472 B; stride 37: conflict-free reads
    int tid = threadIdx.x;
    int lane = tid & 63;
    int wid = __builtin_amdgcn_readfirstlane(tid >> 6);
    int blk = blockIdx.x;                    // 0..1023
    int sg = (blk & 7) * 128 + (blk >> 3);   // XCD-contiguous strip id
    int b = sg >> 8;
    int hwbase = (sg & 255) * 64;
    int n = lane & 15, q = lane >> 4;
    int hw = hwbase + wid * 16 + n;
    int y = hw >> 7, x = hw & (W - 1);

    const unsigned short* xb = xcat + (size_t)b * HW * CST;   // plane-major base
    const unsigned short* pl0 = xb + (((size_t)q * HW) << 3);        // plane q (ks0)
    const unsigned short* pl1 = xb + (((size_t)(4 + q) * HW) << 3);  // plane 4+q (ks1)
    const float* lb_ = lrp + (size_t)b * HW * 4;

    // ---------------- phase 1: offset+mask conv (all 9 taps, this wave) ---
    {
        f32x4 acc2[2];
#pragma unroll
        for (int mt = 0; mt < 2; mt++) { f32x4 z = {0.f, 0.f, 0.f, 0.f}; acc2[mt] = z; }
#pragma unroll
        for (int tap = 0; tap < K2; tap++) {
            int ky = tap / 3, kx = tap - ky * 3;
            int yy = y + ky - 1, xx = x + kx - 1;
            bool vld = (yy >= 0 && yy < H && xx >= 0 && xx < W);
            int ii = min(max(yy, 0), H - 1) * W + min(max(xx, 0), W - 1);
            const unsigned short* ab = apkom + (size_t)(tap * 6) * 512 + lane * 8;
            // kss = 0: plane q; kss = 1: plane 4+q (coalesced across n)
            {
                bf16x8 bfv = *(const bf16x8*)(pl0 + ((size_t)ii << 3));
                if (!vld) { bf16x8 z = {0, 0, 0, 0, 0, 0, 0, 0}; bfv = z; }
#pragma unroll
                for (int mt = 0; mt < 2; mt++) {
                    bf16x8 af = *(const bf16x8*)(ab + (size_t)(0 * 2 + mt) * 512);
                    acc2[mt] = __builtin_amdgcn_mfma_f32_16x16x32_bf16(af, bfv, acc2[mt], 0, 0, 0);
                }
            }
            {
                bf16x8 bfv = *(const bf16x8*)(pl1 + ((size_t)ii << 3));
                if (!vld) { bf16x8 z = {0, 0, 0, 0, 0, 0, 0, 0}; bfv = z; }
#pragma unroll
                for (int mt = 0; mt < 2; mt++) {
                    bf16x8 af = *(const bf16x8*)(ab + (size_t)(1 * 2 + mt) * 512);
                    acc2[mt] = __builtin_amdgcn_mfma_f32_16x16x32_bf16(af, bfv, acc2[mt], 0, 0, 0);
                }
            }
            // kss = 2: lr channels (c 64..66) carried by q==0 lanes only
            bf16x8 bf2 = {0, 0, 0, 0, 0, 0, 0, 0};
            if (q == 0 && vld) {
                f32x4 L = *(const f32x4*)(lb_ + ((size_t)ii << 2));
#pragma unroll
                for (int j = 0; j < 4; j++) bf2[j] = (short)f2bf(L[j]);
            }
#pragma unroll
            for (int mt = 0; mt < 2; mt++) {
                bf16x8 af = *(const bf16x8*)(ab + (size_t)(4 + mt) * 512);
                acc2[mt] = __builtin_amdgcn_mfma_f32_16x16x32_bf16(af, bf2, acc2[mt], 0, 0, 0);
            }
        }
        // LDS transpose: lane (n,q) holds o = mt*16+q*4+r for pixel n
#pragma unroll
        for (int mt = 0; mt < 2; mt++)
#pragma unroll
            for (int r = 0; r < 4; r++) {
                int o = mt * 16 + q * 4 + r;
                float s = acc2[mt][r];
                if (o < 18)
                    somp[wid][n][(o >> 1) * 4 + (o & 1)] = s + ob[o];
                else if (o < 27)
                    somp[wid][n][(o - 18) * 4 + 2] = 2.f * fast_sigmoid(s + mb[o - 18]);
            }
    }
    __syncthreads();

    // ---------------- phase 2: deformable conv (all 9 taps, this wave) ----
    f32x4 acc[4];
#pragma unroll
    for (int mt = 0; mt < 4; mt++) { f32x4 z = {0.f, 0.f, 0.f, 0.f}; acc[mt] = z; }

#pragma unroll
    for (int tap = 0; tap < K2; tap++) {
        float omy = somp[wid][n][tap * 4 + 0];
        float omx = somp[wid][n][tap * 4 + 1];
        float m = somp[wid][n][tap * 4 + 2];
        int ky = tap / 3, kx = tap - ky * 3;
        float py = (float)(y + ky - 1) + omy;
        float px_ = (float)(x + kx - 1) + omx;
        float fy = floorf(py), fx = floorf(px_);
        float wy = py - fy, wx = px_ - fx;
        int y0 = (int)fy, x0 = (int)fx;
        int y1 = y0 + 1, x1 = x0 + 1;
        float vy0 = (y0 >= 0 && y0 <= H - 1) ? 1.f : 0.f;
        float vy1 = (y1 >= 0 && y1 <= H - 1) ? 1.f : 0.f;
        float vx0 = (x0 >= 0 && x0 <= W - 1) ? 1.f : 0.f;
        float vx1 = (x1 >= 0 && x1 <= W - 1) ? 1.f : 0.f;
        int yc0 = min(max(y0, 0), H - 1), yc1 = min(max(y1, 0), H - 1);
        int xc0 = min(max(x0, 0), W - 1), xc1 = min(max(x1, 0), W - 1);
        float a00 = (1.f - wy) * (1.f - wx) * m * vy0 * vx0;
        float a01 = (1.f - wy) * wx * m * vy0 * vx1;
        float a10 = wy * (1.f - wx) * m * vy1 * vx0;
        float a11 = wy * wx * m * vy1 * vx1;
        int j00 = yc0 * W + xc0, j01 = yc0 * W + xc1;
        int j10 = yc1 * W + xc0, j11 = yc1 * W + xc1;

        const unsigned short* ab = apk + (size_t)(tap * 12) * 512 + lane * 8;
        // ks = 0: plane q — coalesced when j(n) runs are consecutive
        {
            u32x4 d00 = *(const u32x4*)(pl0 + ((size_t)j00 << 3));
            u32x4 d01 = *(const u32x4*)(pl0 + ((size_t)j01 << 3));
            u32x4 d10 = *(const u32x4*)(pl0 + ((size_t)j10 << 3));
            u32x4 d11 = *(const u32x4*)(pl0 + ((size_t)j11 << 3));
            bf16x8 bf;
            unsigned int* bfu = (unsigned int*)&bf;
#pragma unroll
            for (int e = 0; e < 4; e++) {
                f32x2 v = unpk(d00[e]) * a00 + unpk(d01[e]) * a01
                        + unpk(d10[e]) * a10 + unpk(d11[e]) * a11;
                bfu[e] = (unsigned int)f2bf(v[0]) | ((unsigned int)f2bf(v[1]) << 16);
            }
#pragma unroll
            for (int mt = 0; mt < 4; mt++) {
                bf16x8 af = *(const bf16x8*)(ab + (size_t)(0 * 4 + mt) * 512);
                acc[mt] = __builtin_amdgcn_mfma_f32_16x16x32_bf16(af, bf, acc[mt], 0, 0, 0);
            }
        }
        // ks = 1: plane 4+q
        {
            u32x4 d00 = *(const u32x4*)(pl1 + ((size_t)j00 << 3));
            u32x4 d01 = *(const u32x4*)(pl1 + ((size_t)j01 << 3));
            u32x4 d10 = *(const u32x4*)(pl1 + ((size_t)j10 << 3));
            u32x4 d11 = *(const u32x4*)(pl1 + ((size_t)j11 << 3));
            bf16x8 bf;
            unsigned int* bfu = (unsigned int*)&bf;
#pragma unroll
            for (int e = 0; e < 4; e++) {
                f32x2 v = unpk(d00[e]) * a00 + unpk(d01[e]) * a01
                        + unpk(d10[e]) * a10 + unpk(d11[e]) * a11;
                bfu[e] = (unsigned int)f2bf(v[0]) | ((unsigned int)f2bf(v[1]) << 16);
            }
#pragma unroll
            for (int mt = 0; mt < 4; mt++) {
                bf16x8 af = *(const bf16x8*)(ab + (size_t)(1 * 4 + mt) * 512);
                acc[mt] = __builtin_amdgcn_mfma_f32_16x16x32_bf16(af, bf, acc[mt], 0, 0, 0);
            }
        }
        // ks = 2: lr channels via q==0 lanes
        bf16x8 bf2 = {0, 0, 0, 0, 0, 0, 0, 0};
        if (q == 0) {
            f32x4 L00 = *(const f32x4*)(lb_ + ((size_t)j00 << 2));
            f32x4 L01 = *(const f32x4*)(lb_ + ((size_t)j01 << 2));
            f32x4 L10 = *(const f32x4*)(lb_ + ((size_t)j10 << 2));
            f32x4 L11 = *(const f32x4*)(lb_ + ((size_t)j11 << 2));
            f32x4 Lv = L00 * a00 + L01 * a01 + L10 * a10 + L11 * a11;
#pragma unroll
            for (int j = 0; j < 4; j++) bf2[j] = (short)f2bf(Lv[j]);
        }
#pragma unroll
        for (int mt = 0; mt < 4; mt++) {
            bf16x8 af = *(const bf16x8*)(ab + (size_t)(2 * 4 + mt) * 512);
            acc[mt] = __builtin_amdgcn_mfma_f32_16x16x32_bf16(af, bf2, acc[mt], 0, 0, 0);
        }
    }

    // direct epilogue: lane (n,q) stores o = mt*16+q*4+r (plane-major)
    unsigned short* xo = xout + (size_t)b * HW * CST;
#pragma unroll
    for (int mt = 0; mt < 4; mt++) {
        float s[4];
#pragma unroll
        for (int r = 0; r < 4; r++) {
            int o = mt * 16 + q * 4 + r;
            s[r] = acc[mt][r] + bias[o];
        }
        u32x2 st;
        st[0] = (unsigned int)f2bf(s[0]) | ((unsigned int)f2bf(s[1]) << 16);
        st[1] = (unsigned int)f2bf(s[2]) | ((unsigned int)f2bf(s[3]) << 16);
        int p = 2 * mt + (q >> 1);
        *(u32x2*)(xo + (((size_t)p * HW + hw) << 3) + (q & 1) * 4) = st;
    }
}

// ---------------------------------------------------------------------------
// Final 3-channel conv, tap-split across 4 waves with LDS reduction.
// Plane-major xcat reads: adjacent lanes (adjacent px) now coalesce.
// ---------------------------------------------------------------------------
__global__ __launch_bounds__(256, 4) void k_conv3(const unsigned short* __restrict__ xcat,
                                                  const float* __restrict__ lrp,
                                                  const float* __restrict__ cw,
                                                  const float* __restrict__ cb,
                                                  float* __restrict__ y3) {
    __shared__ float red[4 * 3 * 64];  // 3072 B
    int tid = threadIdx.x;
    int lane = tid & 63;
    int wid = __builtin_amdgcn_readfirstlane(tid >> 6);
    int blk = blockIdx.x;
    int sg = (blk & 7) * 128 + (blk >> 3);
    int b = sg >> 8;
    int hwbase = (sg & 255) * 64;
    int hw = hwbase + lane;
    int y = hw >> 7, x = hw & (W - 1);
    int t0 = (wid == 0) ? 0 : 3 + (wid - 1) * 2;
    int t1 = (wid == 0) ? 3 : t0 + 2;

    float a0 = 0.f, a1 = 0.f, a2 = 0.f;
    const unsigned short* xb = xcat + (size_t)b * HW * CST;
    const float* lb_ = lrp + (size_t)b * HW * 4;
#pragma unroll 1
    for (int tap = t0; tap < t1; tap++) {
        int ky = tap / 3, kx = tap - ky * 3;
        int yy = y + ky - 1, xx = x + kx - 1;
        if (yy < 0 || yy >= H || xx < 0 || xx >= W) continue;
        int ii = yy * W + xx;
#pragma unroll
        for (int c8 = 0; c8 < 8; c8++) {
            u32x4 d = *(const u32x4*)(xb + (((size_t)c8 * HW + ii) << 3));
#pragma unroll
            for (int e = 0; e < 4; e++) {
                int c = c8 * 8 + e * 2;
                float lo = __uint_as_float(d[e] << 16);
                float hi = __uint_as_float(d[e] & 0xffff0000u);
                a0 += lo * cw[0 * (CIN * 9) + c * 9 + tap] + hi * cw[0 * (CIN * 9) + (c + 1) * 9 + tap];
                a1 += lo * cw[1 * (CIN * 9) + c * 9 + tap] + hi * cw[1 * (CIN * 9) + (c + 1) * 9 + tap];
                a2 += lo * cw[2 * (CIN * 9) + c * 9 + tap] + hi * cw[2 * (CIN * 9) + (c + 1) * 9 + tap];
            }
        }
        f32x4 L = *(const f32x4*)(lb_ + ((size_t)ii << 2));
#pragma unroll
        for (int e = 0; e < 3; e++) {
            a0 += L[e] * cw[0 * (CIN * 9) + (64 + e) * 9 + tap];
            a1 += L[e] * cw[1 * (CIN * 9) + (64 + e) * 9 + tap];
            a2 += L[e] * cw[2 * (CIN * 9) + (64 + e) * 9 + tap];
        }
    }
    red[(wid * 3 + 0) * 64 + lane] = a0;
    red[(wid * 3 + 1) * 64 + lane] = a1;
    red[(wid * 3 + 2) * 64 + lane] = a2;
    __syncthreads();
    if (tid < 192) {
        int oc = tid >> 6, px = tid & 63;
        float s = red[(0 * 3 + oc) * 64 + px] + red[(1 * 3 + oc) * 64 + px]
                + red[(2 * 3 + oc) * 64 + px] + red[(3 * 3 + oc) * 64 + px];
        y3[(size_t)(b * NC + oc) * HW + hwbase + px] = s + cb[oc];
    }
}

// global average pool: one block per (b,c)
__global__ __launch_bounds__(256) void k_pool(const float* __restrict__ y3,
                                              float* __restrict__ pooled) {
    int bc = blockIdx.x;  // 0..11
    const float* p = y3 + (size_t)bc * HW;
    float s = 0.f;
    for (int i = threadIdx.x; i < HW; i += 256) s += p[i];
    __shared__ float red[256];
    red[threadIdx.x] = s;
    __syncthreads();
    for (int off = 128; off > 0; off >>= 1) {
        if (threadIdx.x < off) red[threadIdx.x] += red[threadIdx.x + off];
        __syncthreads();
    }
    if (threadIdx.x == 0) pooled[bc] = red[0] / (float)HW;
}

// ---------------------------------------------------------------------------
// Fused DDF upsample: spatial conv + dynamic combine + pixel_shuffle + clip.
// Computes the tiny per-branch channel MLP in-block (fused k_ch).
// ---------------------------------------------------------------------------
__global__ __launch_bounds__(256) void k_ddf(const float* __restrict__ y3,
                                             const float* __restrict__ spw,
                                             const float* __restrict__ spb,
                                             const float* __restrict__ pooled,
                                             const float* __restrict__ ch_w1,
                                             const float* __restrict__ ch_b1,
                                             const float* __restrict__ ch_w2,
                                             const float* __restrict__ ch_b2,
                                             float* __restrict__ out) {
    __shared__ float s_spw[4 * K2 * NC * 9];  // 972
    __shared__ float s_spb[4 * K2];           // 36
    __shared__ float s_ch[4 * NC * K2];       // 108
    int t = blockIdx.x * blockDim.x + threadIdx.x;
    int b = t >> 14, hw = t & (HW - 1), y = hw >> 7, x = hw & (W - 1);
    int s0 = blockIdx.y * 4;
    for (int i = threadIdx.x; i < 4 * K2 * NC * 9; i += 256) s_spw[i] = spw[s0 * K2 * NC * 9 + i];
    if (threadIdx.x < 4 * K2) s_spb[threadIdx.x] = spb[s0 * K2 + threadIdx.x];
    if (threadIdx.x < 4 * NC * K2) {
        int t2 = threadIdx.x;
        int si = t2 / (NC * K2), kk = t2 - si * (NC * K2);
        int s = s0 + si;
        float a = ch_b2[s * (NC * K2) + kk];
#pragma unroll
        for (int m = 0; m < MID; m++) {
            float h1 = ch_b1[s * MID + m];
#pragma unroll
            for (int c = 0; c < NC; c++) h1 += pooled[b * NC + c] * ch_w1[(s * MID + m) * NC + c];
            a += fmaxf(h1, 0.f) * ch_w2[(s * (NC * K2) + kk) * MID + m];
        }
        s_ch[t2] = a;
    }
    __syncthreads();
    float p[NC][9];
#pragma unroll
    for (int c = 0; c < NC; c++) load_patch(y3 + (b * NC + c) * HW, y, x, p[c]);
#pragma unroll
    for (int si = 0; si < 4; si++) {
        int s = s0 + si;
        float spv[K2];
#pragma unroll
        for (int k = 0; k < K2; k++) {
            float a = s_spb[si * K2 + k];
            const float* w = s_spw + (si * K2 + k) * (NC * 9);
#pragma unroll
            for (int c = 0; c < NC; c++)
#pragma unroll
                for (int tt = 0; tt < 9; tt++) a += p[c][tt] * w[c * 9 + tt];
            spv[k] = a;
        }
        int sy = s >> 2, sx = s & 3;
#pragma unroll
        for (int c = 0; c < NC; c++) {
            float a = 0.f;
            const float* chp = s_ch + (si * NC + c) * K2;
#pragma unroll
            for (int k = 0; k < K2; k++) a += p[c][k] * (chp[k] + spv[k]);
            a = fminf(fmaxf(a, 0.f), 255.f);
            out[((size_t)(b * NC + c) * OUT_HW + (y * SCALE + sy)) * OUT_HW + (x * SCALE + sx)] = a;
        }
    }
}

extern "C" void kernel_launch(void* const* d_in, const int* in_sizes, int n_in,
                              void* d_out, int out_size, void* d_ws, size_t ws_size,
                              hipStream_t stream) {
    const float* X = (const float*)d_in[0];
    const float* lstm_w = (const float*)d_in[1];
    const float* lstm_b = (const float*)d_in[2];
    const float* ow[3] = {(const float*)d_in[3], (const float*)d_in[9], (const float*)d_in[15]};
    const float* ob[3] = {(const float*)d_in[4], (const float*)d_in[10], (const float*)d_in[16]};
    const float* mw[3] = {(const float*)d_in[5], (const float*)d_in[11], (const float*)d_in[17]};
    const float* mb[3] = {(const float*)d_in[6], (const float*)d_in[12], (const float*)d_in[18]};
    const float* dw[3] = {(const float*)d_in[7], (const float*)d_in[13], (const float*)d_in[19]};
    const float* db[3] = {(const float*)d_in[8], (const float*)d_in[14], (const float*)d_in[20]};
    const float* conv_w = (const float*)d_in[21];
    const float* conv_b = (const float*)d_in[22];
    const float* sp_w = (const float*)d_in[23];
    const float* sp_b = (const float*)d_in[24];
    const float* ch_w1 = (const float*)d_in[25];
    const float* ch_b1 = (const float*)d_in[26];
    const float* ch_w2 = (const float*)d_in[27];
    const float* ch_b2 = (const float*)d_in[28];

    float* out = (float*)d_out;
    const size_t OUT_IMG = (size_t)B * NC * OUT_HW * OUT_HW;  // 3145728
    const size_t HIDSZ = (size_t)B * NK * HW;                 // 4194304
    float* hid_out = out + OUT_IMG;
    float* cell_out = out + OUT_IMG + HIDSZ;

    float* ws = (float*)d_ws;
    const size_t XCATF = (size_t)B * HW * CST / 2;  // bf16 xcat, in float units
    unsigned short* xcatA = (unsigned short*)ws;  ws += XCATF;
    unsigned short* xcatB = (unsigned short*)ws;  ws += XCATF;
    float* lrp = ws;              ws += (size_t)B * HW * 4;
    unsigned short* apk[3];
    for (int i = 0; i < 3; i++) { apk[i] = (unsigned short*)ws; ws += 108 * 512 / 2; }
    unsigned short* apkOM[3];
    for (int i = 0; i < 3; i++) { apkOM[i] = (unsigned short*)ws; ws += 54 * 512 / 2; }
    unsigned short* aplk = (unsigned short*)ws;  ws += 12 * 512 / 2;
    float* y3 = ws;               ws += (size_t)B * NC * HW;
    float* pooled = ws;           ws += 16;

    dim3 blk(256);
    dim3 g4(B * HW / 256, 4);
    dim3 gd(B * HW / 64);         // 1024 strips (64 px per block, 16 per wave)

    k_prepL<<<dim3(12), dim3(512), 0, stream>>>(lstm_w, aplk);
    for (int i = 0; i < 3; i++) {
        k_prepA<<<dim3(108), dim3(512), 0, stream>>>(dw[i], apk[i]);
        k_prepOM<<<dim3(54), dim3(512), 0, stream>>>(ow[i], mw[i], apkOM[i]);
    }
    k_lstm<<<gd, blk, 0, stream>>>(X, aplk, lstm_b, xcatA, hid_out, cell_out, lrp);

    // layer 1: xcatA -> xcatB (offmask fused into deform, plane-major xcat)
    k_offdef<<<gd, blk, 0, stream>>>(xcatA, lrp, apkOM[0], ob[0], mb[0], apk[0], db[0], xcatB);
    // layer 2: xcatB -> xcatA
    k_offdef<<<gd, blk, 0, stream>>>(xcatB, lrp, apkOM[1], ob[1], mb[1], apk[1], db[1], xcatA);
    // layer 3: xcatA -> xcatB
    k_offdef<<<gd, blk, 0, stream>>>(xcatA, lrp, apkOM[2], ob[2], mb[2], apk[2], db[2], xcatB);

    k_conv3<<<gd, blk, 0, stream>>>(xcatB, lrp, conv_w, conv_b, y3);
    k_pool<<<dim3(B * NC), blk, 0, stream>>>(y3, pooled);
    k_ddf<<<g4, blk, 0, stream>>>(y3, sp_w, sp_b, pooled, ch_w1, ch_b1, ch_w2, ch_b2, out);
}